// Round 2
// baseline (133.457 us; speedup 1.0000x reference)
//
#include <hip/hip_runtime.h>

#define NB 4096
#define NPATCH 196
#define BS 32
#define KT 16

// ---------------- Kernel 1: quanvolution ----------------
// One thread = one 2x2 patch = one 4-qubit (16 complex amp) circuit sim.
__global__ __launch_bounds__(256) void quanv_kernel(
    const float* __restrict__ x, const float* __restrict__ qp,
    float* __restrict__ feats)
{
    int t = blockIdx.x * 256 + threadIdx.x;
    if (t >= NB * NPATCH) return;
    int b = t / NPATCH;
    int p = t - b * NPATCH;
    int pi = p / 14;
    int pj = p - pi * 14;

    const float* img = x + b * 784 + (2 * pi) * 28 + 2 * pj;
    float2 top = *reinterpret_cast<const float2*>(img);
    float2 bot = *reinterpret_cast<const float2*>(img + 28);
    float ang[4] = {top.x, top.y, bot.x, bot.y};

    float vc[4], vs[4];
#pragma unroll
    for (int q = 0; q < 4; ++q) __sincosf(0.5f * ang[q], &vs[q], &vc[q]);

    // state index = a*8 + b*4 + c*2 + d  (wire0=bit3 ... wire3=bit0)
    float re[16], im[16];
#pragma unroll
    for (int i = 0; i < 16; ++i) {
        re[i] = ((i & 8) ? vs[0] : vc[0]) * ((i & 4) ? vs[1] : vc[1]) *
                ((i & 2) ? vs[2] : vc[2]) * ((i & 1) ? vs[3] : vc[3]);
        im[i] = 0.0f;
    }

    float gc, gs;

    // RX(theta0) on wire 0 (stride 8): [[c,-is],[-is,c]]
    __sincosf(0.5f * qp[0], &gs, &gc);
#pragma unroll
    for (int i = 0; i < 16; ++i) if (!(i & 8)) {
        int j = i | 8;
        float r0 = re[i], i0 = im[i], r1 = re[j], i1 = im[j];
        re[i] = gc * r0 + gs * i1; im[i] = gc * i0 - gs * r1;
        re[j] = gc * r1 + gs * i0; im[j] = gc * i1 - gs * r0;
    }
    // RY(theta1) on wire 1 (stride 4): [[c,-s],[s,c]]
    __sincosf(0.5f * qp[1], &gs, &gc);
#pragma unroll
    for (int i = 0; i < 16; ++i) if (!(i & 4)) {
        int j = i | 4;
        float r0 = re[i], i0 = im[i], r1 = re[j], i1 = im[j];
        re[i] = gc * r0 - gs * r1; im[i] = gc * i0 - gs * i1;
        re[j] = gs * r0 + gc * r1; im[j] = gs * i0 + gc * i1;
    }
    // RZ(theta2) on wire 2 (stride 2): diag(e^{-it/2}, e^{+it/2})
    __sincosf(0.5f * qp[2], &gs, &gc);
#pragma unroll
    for (int i = 0; i < 16; ++i) if (!(i & 2)) {
        int j = i | 2;
        float r0 = re[i], i0 = im[i], r1 = re[j], i1 = im[j];
        re[i] = gc * r0 + gs * i0; im[i] = gc * i0 - gs * r0;
        re[j] = gc * r1 - gs * i1; im[j] = gc * i1 + gs * r1;
    }
    // CNOT(0,1): ctrl bit3(8), tgt bit2(4)
#pragma unroll
    for (int i = 0; i < 16; ++i) if ((i & 8) && !(i & 4)) {
        int j = i | 4;
        float tr = re[i], ti = im[i];
        re[i] = re[j]; im[i] = im[j];
        re[j] = tr;    im[j] = ti;
    }
    // RX(theta3) on wire 3 (stride 1)
    __sincosf(0.5f * qp[3], &gs, &gc);
#pragma unroll
    for (int i = 0; i < 16; ++i) if (!(i & 1)) {
        int j = i | 1;
        float r0 = re[i], i0 = im[i], r1 = re[j], i1 = im[j];
        re[i] = gc * r0 + gs * i1; im[i] = gc * i0 - gs * r1;
        re[j] = gc * r1 + gs * i0; im[j] = gc * i1 - gs * r0;
    }
    // CNOT(2,3): ctrl bit1(2), tgt bit0(1)
#pragma unroll
    for (int i = 0; i < 16; ++i) if ((i & 2) && !(i & 1)) {
        int j = i | 1;
        float tr = re[i], ti = im[i];
        re[i] = re[j]; im[i] = im[j];
        re[j] = tr;    im[j] = ti;
    }
    // RY(theta4) on wire 0 (stride 8)
    __sincosf(0.5f * qp[4], &gs, &gc);
#pragma unroll
    for (int i = 0; i < 16; ++i) if (!(i & 8)) {
        int j = i | 8;
        float r0 = re[i], i0 = im[i], r1 = re[j], i1 = im[j];
        re[i] = gc * r0 - gs * r1; im[i] = gc * i0 - gs * i1;
        re[j] = gs * r0 + gc * r1; im[j] = gs * i0 + gc * i1;
    }
    // CNOT(1,2): ctrl bit2(4), tgt bit1(2)
#pragma unroll
    for (int i = 0; i < 16; ++i) if ((i & 4) && !(i & 2)) {
        int j = i | 2;
        float tr = re[i], ti = im[i];
        re[i] = re[j]; im[i] = im[j];
        re[j] = tr;    im[j] = ti;
    }

    // Z expectations per wire
    float e0 = 0.f, e1 = 0.f, e2 = 0.f, e3 = 0.f;
#pragma unroll
    for (int i = 0; i < 16; ++i) {
        float pr = re[i] * re[i] + im[i] * im[i];
        e0 += (i & 8) ? -pr : pr;
        e1 += (i & 4) ? -pr : pr;
        e2 += (i & 2) ? -pr : pr;
        e3 += (i & 1) ? -pr : pr;
    }
    *reinterpret_cast<float4*>(feats + b * 784 + p * 4) =
        make_float4(e0, e1, e2, e3);
}

// ---------------- Kernel 2: fused MLP ----------------
// Block: 32 samples x all 128 hidden units (so layer 2 fuses in-block).
// 256 threads, 4x4 fp32 accumulators each, KT=16 K-tile.
__global__ __launch_bounds__(256) void mlp_kernel(
    const float* __restrict__ feats,
    const float* __restrict__ W1, const float* __restrict__ b1,
    const float* __restrict__ W2, const float* __restrict__ b2,
    float* __restrict__ out)
{
    __shared__ float At[KT][40];     // [kk][sample], padded to 40 (16B-aligned rows)
    __shared__ float Bt[KT][128];    // [kk][unit]
    __shared__ float Ht[BS][128];    // hidden activations
    __shared__ float W2s[10 * 128];

    const int t = threadIdx.x;
    const int bs = blockIdx.x * BS;

    for (int o = t; o < 1280; o += 256) W2s[o] = W2[o];

    const int tx = t & 31, ty = t >> 5;
    const int sy = ty * 4, ux = tx * 4;
    const int as = t >> 3, ak = (t & 7) * 2;   // A-staging: float2 per thread
    const int bu = t >> 1, bk = (t & 1) * 8;   // B-staging: 8 floats per thread

    float acc[4][4] = {{0.f}};

    const float* aptr = feats + (bs + as) * 784 + ak;
    const float* bptr = W1 + bu * 784 + bk;

    for (int k0 = 0; k0 < 784; k0 += KT) {
        float2 av  = *reinterpret_cast<const float2*>(aptr + k0);
        float4 bv0 = *reinterpret_cast<const float4*>(bptr + k0);
        float4 bv1 = *reinterpret_cast<const float4*>(bptr + k0 + 4);
        __syncthreads();
        At[ak][as]     = av.x;
        At[ak + 1][as] = av.y;
        Bt[bk + 0][bu] = bv0.x; Bt[bk + 1][bu] = bv0.y;
        Bt[bk + 2][bu] = bv0.z; Bt[bk + 3][bu] = bv0.w;
        Bt[bk + 4][bu] = bv1.x; Bt[bk + 5][bu] = bv1.y;
        Bt[bk + 6][bu] = bv1.z; Bt[bk + 7][bu] = bv1.w;
        __syncthreads();
#pragma unroll
        for (int kk = 0; kk < KT; ++kk) {
            float4 a  = *reinterpret_cast<const float4*>(&At[kk][sy]);
            float4 bb = *reinterpret_cast<const float4*>(&Bt[kk][ux]);
            float ar[4] = {a.x, a.y, a.z, a.w};
            float br[4] = {bb.x, bb.y, bb.z, bb.w};
#pragma unroll
            for (int i = 0; i < 4; ++i)
#pragma unroll
                for (int j = 0; j < 4; ++j)
                    acc[i][j] = fmaf(ar[i], br[j], acc[i][j]);
        }
    }

    // bias + relu -> Ht
#pragma unroll
    for (int j = 0; j < 4; ++j) {
        float bj = b1[ux + j];
#pragma unroll
        for (int i = 0; i < 4; ++i) {
            float h = acc[i][j] + bj;
            Ht[sy + i][ux + j] = fmaxf(h, 0.0f);
        }
    }
    __syncthreads();

    // layer 2: 32 samples x 10 logits
    for (int o = t; o < BS * 10; o += 256) {
        int s = o / 10;
        int j = o - s * 10;
        float sum = b2[j];
        const float* hrow = Ht[s];
        const float* wrow = W2s + j * 128;
#pragma unroll 8
        for (int u = 0; u < 128; ++u) sum = fmaf(hrow[u], wrow[u], sum);
        out[(bs + s) * 10 + j] = sum;
    }
}

extern "C" void kernel_launch(void* const* d_in, const int* in_sizes, int n_in,
                              void* d_out, int out_size, void* d_ws, size_t ws_size,
                              hipStream_t stream)
{
    const float* x  = (const float*)d_in[0];
    const float* qp = (const float*)d_in[1];
    const float* W1 = (const float*)d_in[2];
    const float* b1 = (const float*)d_in[3];
    const float* W2 = (const float*)d_in[4];
    const float* b2 = (const float*)d_in[5];
    float* out   = (float*)d_out;
    float* feats = (float*)d_ws;   // 4096*784 f32 = 12.85 MB scratch

    int total = NB * NPATCH;
    quanv_kernel<<<(total + 255) / 256, 256, 0, stream>>>(x, qp, feats);
    mlp_kernel<<<NB / BS, 256, 0, stream>>>(feats, W1, b1, W2, b2, out);
}

// Round 4
// 129.863 us; speedup vs baseline: 1.0277x; 1.0277x over previous
//
#include <hip/hip_runtime.h>

#define NB 4096
#define NPATCH 196
#define KP 800   // K=784 zero-padded to 800 (25 x 32)

typedef __attribute__((ext_vector_type(8))) short short8;
typedef __attribute__((ext_vector_type(4))) float f32x4;

__device__ __forceinline__ ushort f2bf(float f) {
    unsigned b = __builtin_bit_cast(unsigned, f);
    b += 0x7FFFu + ((b >> 16) & 1u);   // RNE
    return (ushort)(b >> 16);
}

// ---------------- Kernel 1: quanvolution ----------------
// One thread = one 2x2 patch = 4-qubit (16 complex amp) circuit sim.
// __sinf/__cosf (no address-taken outputs -> no scratch risk). bf16 output.
__global__ __launch_bounds__(256) void quanv_kernel(
    const float* __restrict__ x, const float* __restrict__ qp,
    ushort* __restrict__ fb)
{
    int t = blockIdx.x * 256 + threadIdx.x;
    if (t >= NB * NPATCH) return;
    int b = t / NPATCH;
    int p = t - b * NPATCH;
    int pi = p / 14;
    int pj = p - pi * 14;

    const float* img = x + b * 784 + (2 * pi) * 28 + 2 * pj;
    float2 top = *reinterpret_cast<const float2*>(img);
    float2 bot = *reinterpret_cast<const float2*>(img + 28);
    float ang[4] = {top.x, top.y, bot.x, bot.y};

    float vc[4], vs[4];
#pragma unroll
    for (int q = 0; q < 4; ++q) {
        vs[q] = __sinf(0.5f * ang[q]);
        vc[q] = __cosf(0.5f * ang[q]);
    }

    // state index = a*8 + b*4 + c*2 + d  (wire0=bit3 ... wire3=bit0)
    float re[16], im[16];
#pragma unroll
    for (int i = 0; i < 16; ++i) {
        re[i] = ((i & 8) ? vs[0] : vc[0]) * ((i & 4) ? vs[1] : vc[1]) *
                ((i & 2) ? vs[2] : vc[2]) * ((i & 1) ? vs[3] : vc[3]);
        im[i] = 0.0f;
    }

    float gc, gs;

    // RX(theta0) wire 0 (bit 8)
    gs = __sinf(0.5f * qp[0]); gc = __cosf(0.5f * qp[0]);
#pragma unroll
    for (int i = 0; i < 16; ++i) if (!(i & 8)) {
        int j = i | 8;
        float r0 = re[i], i0 = im[i], r1 = re[j], i1 = im[j];
        re[i] = gc * r0 + gs * i1; im[i] = gc * i0 - gs * r1;
        re[j] = gc * r1 + gs * i0; im[j] = gc * i1 - gs * r0;
    }
    // RY(theta1) wire 1 (bit 4)
    gs = __sinf(0.5f * qp[1]); gc = __cosf(0.5f * qp[1]);
#pragma unroll
    for (int i = 0; i < 16; ++i) if (!(i & 4)) {
        int j = i | 4;
        float r0 = re[i], i0 = im[i], r1 = re[j], i1 = im[j];
        re[i] = gc * r0 - gs * r1; im[i] = gc * i0 - gs * i1;
        re[j] = gs * r0 + gc * r1; im[j] = gs * i0 + gc * i1;
    }
    // RZ(theta2) wire 2 (bit 2)
    gs = __sinf(0.5f * qp[2]); gc = __cosf(0.5f * qp[2]);
#pragma unroll
    for (int i = 0; i < 16; ++i) if (!(i & 2)) {
        int j = i | 2;
        float r0 = re[i], i0 = im[i], r1 = re[j], i1 = im[j];
        re[i] = gc * r0 + gs * i0; im[i] = gc * i0 - gs * r0;
        re[j] = gc * r1 - gs * i1; im[j] = gc * i1 + gs * r1;
    }
    // CNOT(0,1)
#pragma unroll
    for (int i = 0; i < 16; ++i) if ((i & 8) && !(i & 4)) {
        int j = i | 4;
        float tr = re[i], ti = im[i];
        re[i] = re[j]; im[i] = im[j];
        re[j] = tr;    im[j] = ti;
    }
    // RX(theta3) wire 3 (bit 1)
    gs = __sinf(0.5f * qp[3]); gc = __cosf(0.5f * qp[3]);
#pragma unroll
    for (int i = 0; i < 16; ++i) if (!(i & 1)) {
        int j = i | 1;
        float r0 = re[i], i0 = im[i], r1 = re[j], i1 = im[j];
        re[i] = gc * r0 + gs * i1; im[i] = gc * i0 - gs * r1;
        re[j] = gc * r1 + gs * i0; im[j] = gc * i1 - gs * r0;
    }
    // CNOT(2,3)
#pragma unroll
    for (int i = 0; i < 16; ++i) if ((i & 2) && !(i & 1)) {
        int j = i | 1;
        float tr = re[i], ti = im[i];
        re[i] = re[j]; im[i] = im[j];
        re[j] = tr;    im[j] = ti;
    }
    // RY(theta4) wire 0 (bit 8)
    gs = __sinf(0.5f * qp[4]); gc = __cosf(0.5f * qp[4]);
#pragma unroll
    for (int i = 0; i < 16; ++i) if (!(i & 8)) {
        int j = i | 8;
        float r0 = re[i], i0 = im[i], r1 = re[j], i1 = im[j];
        re[i] = gc * r0 - gs * r1; im[i] = gc * i0 - gs * i1;
        re[j] = gs * r0 + gc * r1; im[j] = gs * i0 + gc * i1;
    }
    // CNOT(1,2)
#pragma unroll
    for (int i = 0; i < 16; ++i) if ((i & 4) && !(i & 2)) {
        int j = i | 2;
        float tr = re[i], ti = im[i];
        re[i] = re[j]; im[i] = im[j];
        re[j] = tr;    im[j] = ti;
    }

    float e0 = 0.f, e1 = 0.f, e2 = 0.f, e3 = 0.f;
#pragma unroll
    for (int i = 0; i < 16; ++i) {
        float pr = re[i] * re[i] + im[i] * im[i];
        e0 += (i & 8) ? -pr : pr;
        e1 += (i & 4) ? -pr : pr;
        e2 += (i & 2) ? -pr : pr;
        e3 += (i & 1) ? -pr : pr;
    }
    ushort4 o;
    o.x = f2bf(e0); o.y = f2bf(e1); o.z = f2bf(e2); o.w = f2bf(e3);
    *reinterpret_cast<ushort4*>(fb + b * KP + p * 4) = o;
    if (p < 4)   // zero the K-pad 784..799 (4 threads x 4 elems)
        *reinterpret_cast<ushort4*>(fb + b * KP + 784 + p * 4) = make_ushort4(0, 0, 0, 0);
}

// ---------------- Kernel 2: weight conversion to bf16 ----------------
// W1 [128][784] -> W1b [128][KP] zero-padded; W2 [10][128] -> W2b [16][128] zero-padded rows.
__global__ __launch_bounds__(256) void conv_kernel(
    const float* __restrict__ W1, const float* __restrict__ W2,
    ushort* __restrict__ W1b, ushort* __restrict__ W2b)
{
    int t = blockIdx.x * 256 + threadIdx.x;
    if (t < 128 * KP) {
        int r = t / KP, k = t - r * KP;
        W1b[t] = (k < 784) ? f2bf(W1[r * 784 + k]) : (ushort)0;
    } else {
        int u = t - 128 * KP;
        if (u < 16 * 128) W2b[u] = (u < 1280) ? f2bf(W2[u]) : (ushort)0;
    }
}

// ---------------- Kernel 3: MFMA MLP ----------------
// One wave per block; wave tile = 16 samples x 128 units, K-loop 25x32.
// A (feats) and B (W1b, [N][K] = K-major) read DIRECTLY from global:
// lane l reads 16B at row (l&15), k-group (l>>4)*8 -> lanes l,l+16,l+32,l+48
// cover one 64B line. No LDS staging, no barriers in the GEMM.
__global__ __launch_bounds__(64) void mlp_mfma(
    const ushort* __restrict__ fb, const ushort* __restrict__ W1b,
    const float* __restrict__ b1, const ushort* __restrict__ W2b,
    const float* __restrict__ b2, float* __restrict__ out)
{
    __shared__ ushort Hs[16][136];   // 272B rows: 16B-aligned, bank-spread

    const int l = threadIdx.x;
    const int m0 = blockIdx.x * 16;
    const int row = l & 15;          // A-row / B-col within fragment
    const int kg = l >> 4;           // k-group 0..3

    f32x4 acc[8] = {};
    const short8* ap = reinterpret_cast<const short8*>(fb + (m0 + row) * KP + kg * 8);
    const short8* bp[8];
#pragma unroll
    for (int g = 0; g < 8; ++g)
        bp[g] = reinterpret_cast<const short8*>(W1b + (g * 16 + row) * KP + kg * 8);

#pragma unroll 5
    for (int ks = 0; ks < 25; ++ks) {        // k0 = ks*32; short8 stride 8 -> idx ks*4
        short8 a = ap[ks * 4];
#pragma unroll
        for (int g = 0; g < 8; ++g) {
            short8 b = bp[g][ks * 4];
            acc[g] = __builtin_amdgcn_mfma_f32_16x16x32_bf16(a, b, acc[g], 0, 0, 0);
        }
    }

    // bias + relu -> Hs (bf16). C/D layout: col=l&15, row=(l>>4)*4+r.
#pragma unroll
    for (int g = 0; g < 8; ++g) {
        int cc = g * 16 + row;
        float bj = b1[cc];
#pragma unroll
        for (int r = 0; r < 4; ++r) {
            int rr = kg * 4 + r;
            Hs[rr][cc] = f2bf(fmaxf(acc[g][r] + bj, 0.0f));
        }
    }
    __syncthreads();

    // layer 2: D2[16 samples][16 j] = H(16x128) . W2b^T, K=128 in 4 MFMAs
    f32x4 acc2 = {};
#pragma unroll
    for (int ks = 0; ks < 4; ++ks) {
        short8 a = *reinterpret_cast<const short8*>(&Hs[row][ks * 32 + kg * 8]);
        short8 b = *reinterpret_cast<const short8*>(W2b + row * 128 + ks * 32 + kg * 8);
        acc2 = __builtin_amdgcn_mfma_f32_16x16x32_bf16(a, b, acc2, 0, 0, 0);
    }
    if (row < 10) {                  // col j = row; rows kg*4+r are samples
        float bj = b2[row];
#pragma unroll
        for (int r = 0; r < 4; ++r)
            out[(m0 + kg * 4 + r) * 10 + row] = acc2[r] + bj;
    }
}

extern "C" void kernel_launch(void* const* d_in, const int* in_sizes, int n_in,
                              void* d_out, int out_size, void* d_ws, size_t ws_size,
                              hipStream_t stream)
{
    const float* x  = (const float*)d_in[0];
    const float* qp = (const float*)d_in[1];
    const float* W1 = (const float*)d_in[2];
    const float* b1 = (const float*)d_in[3];
    const float* W2 = (const float*)d_in[4];
    const float* b2 = (const float*)d_in[5];
    float* out = (float*)d_out;

    ushort* fb  = (ushort*)d_ws;           // NB*KP bf16      = 6.55 MB
    ushort* W1b = fb + NB * KP;            // 128*KP bf16     = 0.20 MB
    ushort* W2b = W1b + 128 * KP;          // 16*128 bf16     = 4 KB

    quanv_kernel<<<(NB * NPATCH + 255) / 256, 256, 0, stream>>>(x, qp, fb);
    conv_kernel<<<(128 * KP + 16 * 128 + 255) / 256, 256, 0, stream>>>(W1, W2, W1b, W2b);
    mlp_mfma<<<NB / 16, 64, 0, stream>>>(fb, W1b, b1, W2b, b2, out);
}

// Round 5
// 88.421 us; speedup vs baseline: 1.5093x; 1.4687x over previous
//
#include <hip/hip_runtime.h>

#define NB 4096
#define NPATCH 196
#define KP 800   // K=784 zero-padded to 800 (25 x 32)

typedef __attribute__((ext_vector_type(8))) short short8;
typedef __attribute__((ext_vector_type(4))) float f32x4;

__device__ __forceinline__ ushort f2bf(float f) {
    unsigned b = __builtin_bit_cast(unsigned, f);
    b += 0x7FFFu + ((b >> 16) & 1u);   // RNE
    return (ushort)(b >> 16);
}

// ---------------- Kernel 1: weight conversion + gate table ----------------
// W1 [128][784] -> W1b [128][KP] zero-padded; W2 [10][128] -> W2b [16][128];
// block 0 lanes 0-9 also write gtab[10] = {sin,cos}(qp[q]/2).
__global__ __launch_bounds__(256) void conv_kernel(
    const float* __restrict__ W1, const float* __restrict__ W2,
    const float* __restrict__ qp,
    ushort* __restrict__ W1b, ushort* __restrict__ W2b,
    float* __restrict__ gtab)
{
    int t = blockIdx.x * 256 + threadIdx.x;
    if (blockIdx.x == 0 && threadIdx.x < 10) {
        int q = threadIdx.x >> 1;
        float h = 0.5f * qp[q];
        gtab[threadIdx.x] = (threadIdx.x & 1) ? __cosf(h) : __sinf(h);
    }
    if (t < 128 * KP) {
        int r = t / KP, k = t - r * KP;
        W1b[t] = (k < 784) ? f2bf(W1[r * 784 + k]) : (ushort)0;
    } else {
        int u = t - 128 * KP;
        if (u < 16 * 128) W2b[u] = (u < 1280) ? f2bf(W2[u]) : (ushort)0;
    }
}

// ---------------- Kernel 2: quanvolution ----------------
// One thread = one 2x2 patch = 4-qubit (16 complex amp) circuit sim.
// Gate sin/cos read from precomputed uniform table. bf16 output.
__global__ __launch_bounds__(256) void quanv_kernel(
    const float* __restrict__ x, const float* __restrict__ gtab,
    ushort* __restrict__ fb)
{
    int t = blockIdx.x * 256 + threadIdx.x;
    if (t >= NB * NPATCH) return;
    int b = t / NPATCH;
    int p = t - b * NPATCH;
    int pi = p / 14;
    int pj = p - pi * 14;

    const float* img = x + b * 784 + (2 * pi) * 28 + 2 * pj;
    float2 top = *reinterpret_cast<const float2*>(img);
    float2 bot = *reinterpret_cast<const float2*>(img + 28);
    float ang[4] = {top.x, top.y, bot.x, bot.y};

    float vc[4], vs[4];
#pragma unroll
    for (int q = 0; q < 4; ++q) {
        vs[q] = __sinf(0.5f * ang[q]);
        vc[q] = __cosf(0.5f * ang[q]);
    }

    // state index = a*8 + b*4 + c*2 + d  (wire0=bit3 ... wire3=bit0)
    float re[16], im[16];
#pragma unroll
    for (int i = 0; i < 16; ++i) {
        re[i] = ((i & 8) ? vs[0] : vc[0]) * ((i & 4) ? vs[1] : vc[1]) *
                ((i & 2) ? vs[2] : vc[2]) * ((i & 1) ? vs[3] : vc[3]);
        im[i] = 0.0f;
    }

    float gc, gs;

    // RX(theta0) wire 0 (bit 8)
    gs = gtab[0]; gc = gtab[1];
#pragma unroll
    for (int i = 0; i < 16; ++i) if (!(i & 8)) {
        int j = i | 8;
        float r0 = re[i], i0 = im[i], r1 = re[j], i1 = im[j];
        re[i] = gc * r0 + gs * i1; im[i] = gc * i0 - gs * r1;
        re[j] = gc * r1 + gs * i0; im[j] = gc * i1 - gs * r0;
    }
    // RY(theta1) wire 1 (bit 4)
    gs = gtab[2]; gc = gtab[3];
#pragma unroll
    for (int i = 0; i < 16; ++i) if (!(i & 4)) {
        int j = i | 4;
        float r0 = re[i], i0 = im[i], r1 = re[j], i1 = im[j];
        re[i] = gc * r0 - gs * r1; im[i] = gc * i0 - gs * i1;
        re[j] = gs * r0 + gc * r1; im[j] = gs * i0 + gc * i1;
    }
    // RZ(theta2) wire 2 (bit 2)
    gs = gtab[4]; gc = gtab[5];
#pragma unroll
    for (int i = 0; i < 16; ++i) if (!(i & 2)) {
        int j = i | 2;
        float r0 = re[i], i0 = im[i], r1 = re[j], i1 = im[j];
        re[i] = gc * r0 + gs * i0; im[i] = gc * i0 - gs * r0;
        re[j] = gc * r1 - gs * i1; im[j] = gc * i1 + gs * r1;
    }
    // CNOT(0,1)
#pragma unroll
    for (int i = 0; i < 16; ++i) if ((i & 8) && !(i & 4)) {
        int j = i | 4;
        float tr = re[i], ti = im[i];
        re[i] = re[j]; im[i] = im[j];
        re[j] = tr;    im[j] = ti;
    }
    // RX(theta3) wire 3 (bit 1)
    gs = gtab[6]; gc = gtab[7];
#pragma unroll
    for (int i = 0; i < 16; ++i) if (!(i & 1)) {
        int j = i | 1;
        float r0 = re[i], i0 = im[i], r1 = re[j], i1 = im[j];
        re[i] = gc * r0 + gs * i1; im[i] = gc * i0 - gs * r1;
        re[j] = gc * r1 + gs * i0; im[j] = gc * i1 - gs * r0;
    }
    // CNOT(2,3)
#pragma unroll
    for (int i = 0; i < 16; ++i) if ((i & 2) && !(i & 1)) {
        int j = i | 1;
        float tr = re[i], ti = im[i];
        re[i] = re[j]; im[i] = im[j];
        re[j] = tr;    im[j] = ti;
    }
    // RY(theta4) wire 0 (bit 8)
    gs = gtab[8]; gc = gtab[9];
#pragma unroll
    for (int i = 0; i < 16; ++i) if (!(i & 8)) {
        int j = i | 8;
        float r0 = re[i], i0 = im[i], r1 = re[j], i1 = im[j];
        re[i] = gc * r0 - gs * r1; im[i] = gc * i0 - gs * i1;
        re[j] = gs * r0 + gc * r1; im[j] = gs * i0 + gc * i1;
    }
    // CNOT(1,2)
#pragma unroll
    for (int i = 0; i < 16; ++i) if ((i & 4) && !(i & 2)) {
        int j = i | 2;
        float tr = re[i], ti = im[i];
        re[i] = re[j]; im[i] = im[j];
        re[j] = tr;    im[j] = ti;
    }

    float e0 = 0.f, e1 = 0.f, e2 = 0.f, e3 = 0.f;
#pragma unroll
    for (int i = 0; i < 16; ++i) {
        float pr = re[i] * re[i] + im[i] * im[i];
        e0 += (i & 8) ? -pr : pr;
        e1 += (i & 4) ? -pr : pr;
        e2 += (i & 2) ? -pr : pr;
        e3 += (i & 1) ? -pr : pr;
    }
    ushort4 o;
    o.x = f2bf(e0); o.y = f2bf(e1); o.z = f2bf(e2); o.w = f2bf(e3);
    *reinterpret_cast<ushort4*>(fb + b * KP + p * 4) = o;
    if (p < 4)   // zero the K-pad 784..799
        *reinterpret_cast<ushort4*>(fb + b * KP + 784 + p * 4) = make_ushort4(0, 0, 0, 0);
}

// ---------------- Kernel 3: MFMA MLP ----------------
// Block = 256 threads = 4 waves, 16 samples x 128 units. Wave w owns cols
// [w*32, w*32+32) (2 fragments). K-loop = 5 chunks x 5 K-steps, register
// double-buffered (15 loads in flight while 10 MFMAs consume prev chunk).
// All buffer indices static (full unroll) so arrays stay in VGPRs.
__global__ __launch_bounds__(256) void mlp_mfma(
    const ushort* __restrict__ fb, const ushort* __restrict__ W1b,
    const float* __restrict__ b1, const ushort* __restrict__ W2b,
    const float* __restrict__ b2, float* __restrict__ out)
{
    __shared__ ushort Hs[16][136];

    const int t = threadIdx.x;
    const int l = t & 63;
    const int w = t >> 6;            // wave 0..3
    const int m0 = blockIdx.x * 16;
    const int row = l & 15;
    const int kg = l >> 4;

    f32x4 acc0 = {}, acc1 = {};
    const short8* ap  = reinterpret_cast<const short8*>(fb + (m0 + row) * KP + kg * 8);
    const short8* bp0 = reinterpret_cast<const short8*>(W1b + (w * 32 + row) * KP + kg * 8);
    const short8* bp1 = reinterpret_cast<const short8*>(W1b + (w * 32 + 16 + row) * KP + kg * 8);

    short8 A[2][5], B0[2][5], B1[2][5];
#pragma unroll
    for (int s = 0; s < 5; ++s) {
        A[0][s] = ap[s * 4]; B0[0][s] = bp0[s * 4]; B1[0][s] = bp1[s * 4];
    }
#pragma unroll
    for (int c = 0; c < 5; ++c) {
        const int cb = c & 1, nb = cb ^ 1;
        if (c < 4) {
#pragma unroll
            for (int s = 0; s < 5; ++s) {
                int ks = (c + 1) * 5 + s;
                A[nb][s]  = ap[ks * 4];
                B0[nb][s] = bp0[ks * 4];
                B1[nb][s] = bp1[ks * 4];
            }
        }
#pragma unroll
        for (int s = 0; s < 5; ++s) {
            acc0 = __builtin_amdgcn_mfma_f32_16x16x32_bf16(A[cb][s], B0[cb][s], acc0, 0, 0, 0);
            acc1 = __builtin_amdgcn_mfma_f32_16x16x32_bf16(A[cb][s], B1[cb][s], acc1, 0, 0, 0);
        }
    }

    // bias + relu -> Hs (bf16). C/D layout: col=l&15, row=(l>>4)*4+r.
    {
        int cc0 = w * 32 + row, cc1 = cc0 + 16;
        float bj0 = b1[cc0], bj1 = b1[cc1];
#pragma unroll
        for (int r = 0; r < 4; ++r) {
            int rr = kg * 4 + r;
            Hs[rr][cc0] = f2bf(fmaxf(acc0[r] + bj0, 0.0f));
            Hs[rr][cc1] = f2bf(fmaxf(acc1[r] + bj1, 0.0f));
        }
    }
    __syncthreads();

    // layer 2 (wave 0): D2[16 samples][16 j] = H(16x128) . W2b^T
    if (w == 0) {
        f32x4 acc2 = {};
#pragma unroll
        for (int ks = 0; ks < 4; ++ks) {
            short8 a = *reinterpret_cast<const short8*>(&Hs[row][ks * 32 + kg * 8]);
            short8 b = *reinterpret_cast<const short8*>(W2b + row * 128 + ks * 32 + kg * 8);
            acc2 = __builtin_amdgcn_mfma_f32_16x16x32_bf16(a, b, acc2, 0, 0, 0);
        }
        if (row < 10) {
            float bj = b2[row];
#pragma unroll
            for (int r = 0; r < 4; ++r)
                out[(m0 + kg * 4 + r) * 10 + row] = acc2[r] + bj;
        }
    }
}

extern "C" void kernel_launch(void* const* d_in, const int* in_sizes, int n_in,
                              void* d_out, int out_size, void* d_ws, size_t ws_size,
                              hipStream_t stream)
{
    const float* x  = (const float*)d_in[0];
    const float* qp = (const float*)d_in[1];
    const float* W1 = (const float*)d_in[2];
    const float* b1 = (const float*)d_in[3];
    const float* W2 = (const float*)d_in[4];
    const float* b2 = (const float*)d_in[5];
    float* out = (float*)d_out;

    ushort* fb  = (ushort*)d_ws;           // NB*KP bf16      = 6.55 MB
    ushort* W1b = fb + NB * KP;            // 128*KP bf16     = 0.20 MB
    ushort* W2b = W1b + 128 * KP;          // 16*128 bf16     = 4 KB
    float*  gtab = (float*)(W2b + 16 * 128);  // 10 floats

    conv_kernel<<<(128 * KP + 16 * 128 + 255) / 256, 256, 0, stream>>>(W1, W2, qp, W1b, W2b, gtab);
    quanv_kernel<<<(NB * NPATCH + 255) / 256, 256, 0, stream>>>(x, gtab, fb);
    mlp_mfma<<<NB / 16, 256, 0, stream>>>(fb, W1b, b1, W2b, b2, out);
}

// Round 6
// 80.159 us; speedup vs baseline: 1.6649x; 1.1031x over previous
//
#include <hip/hip_runtime.h>

#define NB 4096
#define NPATCH 196
#define KP 800   // K=784 zero-padded to 800 (25 x 32)

typedef __attribute__((ext_vector_type(8))) short short8;
typedef __attribute__((ext_vector_type(4))) float f32x4;

__device__ __forceinline__ ushort f2bf(float f) {
    unsigned b = __builtin_bit_cast(unsigned, f);
    b += 0x7FFFu + ((b >> 16) & 1u);   // RNE
    return (ushort)(b >> 16);
}

// ---------------- Kernel 1: weight conversion + gate table ----------------
// W1 [128][784] -> W1b [128][KP] zero-padded; W2 [10][128] -> W2b [16][128].
// Thread 0 of block 0 writes gtab[7] = {s0h,c0h,s1h,c1h,s4h,c4h,cos(th3)}.
__global__ __launch_bounds__(256) void conv_kernel(
    const float* __restrict__ W1, const float* __restrict__ W2,
    const float* __restrict__ qp,
    ushort* __restrict__ W1b, ushort* __restrict__ W2b,
    float* __restrict__ gtab)
{
    int t = blockIdx.x * 256 + threadIdx.x;
    if (t == 0) {
        gtab[0] = __sinf(0.5f * qp[0]); gtab[1] = __cosf(0.5f * qp[0]);
        gtab[2] = __sinf(0.5f * qp[1]); gtab[3] = __cosf(0.5f * qp[1]);
        gtab[4] = __sinf(0.5f * qp[4]); gtab[5] = __cosf(0.5f * qp[4]);
        gtab[6] = __cosf(qp[3]);
    }
    if (t < 128 * KP) {
        int r = t / KP, k = t - r * KP;
        W1b[t] = (k < 784) ? f2bf(W1[r * 784 + k]) : (ushort)0;
    } else {
        int u = t - 128 * KP;
        if (u < 16 * 128) W2b[u] = (u < 1280) ? f2bf(W2[u]) : (ushort)0;
    }
}

// ---------------- Kernel 2: quanvolution (closed form) ----------------
// Circuit: RX0,RY1,RZ2 | CNOT01 | RX3 | CNOT23 | RY4(w0) | CNOT12.
// RX3 commutes w/ CNOT01; RY4 commutes w/ CNOT23. After RY4 only basis
// permutations remain -> phases never interfere: RZ2 drops out; q2,q3 enter
// via marginals only:
//   M = RY4 . CNOT01 . (u (x) v),  u = RX(t0)(c0,s0), v = RY(t1)(c1,s1)
//   Z0 = sum_b |M(0,b)|^2 - |M(1,b)|^2
//   Z1 = sum_a |M(a,0)|^2 - |M(a,1)|^2
//   Z2 = Z1 * cos(x2)
//   Z3 = cos(t3) * cos(x3) * cos(x2)
__global__ __launch_bounds__(256) void quanv_kernel(
    const float* __restrict__ x, const float* __restrict__ gtab,
    ushort* __restrict__ fb)
{
    int t = blockIdx.x * 256 + threadIdx.x;
    if (t >= NB * NPATCH) return;
    int b = t / NPATCH;
    int p = t - b * NPATCH;
    int pi = p / 14;
    int pj = p - pi * 14;

    const float* img = x + b * 784 + (2 * pi) * 28 + 2 * pj;
    float2 top = *reinterpret_cast<const float2*>(img);        // x0, x1
    float2 bot = *reinterpret_cast<const float2*>(img + 28);   // x2, x3

    float gs0 = gtab[0], gc0 = gtab[1];
    float gs1 = gtab[2], gc1 = gtab[3];
    float gs4 = gtab[4], gc4 = gtab[5];
    float ct3 = gtab[6];

    float c0 = __cosf(0.5f * top.x), s0 = __sinf(0.5f * top.x);
    float c1 = __cosf(0.5f * top.y), s1 = __sinf(0.5f * top.y);
    float cz2 = __cosf(bot.x);
    float cz3 = __cosf(bot.y);

    // u = RX(t0) (c0,s0):  u0 = P - iQ,  u1 = m - i n
    float P = gc0 * c0, Q = gs0 * s0, m = gc0 * s0, n = gs0 * c0;
    // v = RY(t1) (c1,s1)  (real)
    float v0 = gc1 * c1 - gs1 * s1;
    float v1 = gs1 * c1 + gc1 * s1;

    // b=0 column: amp(0,0)=u0*v0, amp(1,0)=u1*v1 (CNOT01), then RY4 mix
    float a0 = gc4 * v0, b0 = gs4 * v1, g0 = gs4 * v0, d0 = gc4 * v1;
    float r, i2;
    r = a0 * P - b0 * m; i2 = a0 * Q - b0 * n; float P00 = r * r + i2 * i2;
    r = g0 * P + d0 * m; i2 = g0 * Q + d0 * n; float P10 = r * r + i2 * i2;
    // b=1 column: amp(0,1)=u0*v1, amp(1,1)=u1*v0
    float a1 = gc4 * v1, b1 = gs4 * v0, g1 = gs4 * v1, d1 = gc4 * v0;
    r = a1 * P - b1 * m; i2 = a1 * Q - b1 * n; float P01 = r * r + i2 * i2;
    r = g1 * P + d1 * m; i2 = g1 * Q + d1 * n; float P11 = r * r + i2 * i2;

    float z0 = (P00 + P01) - (P10 + P11);
    float z1 = (P00 + P10) - (P01 + P11);
    float z2 = z1 * cz2;
    float z3 = ct3 * cz3 * cz2;

    ushort4 o;
    o.x = f2bf(z0); o.y = f2bf(z1); o.z = f2bf(z2); o.w = f2bf(z3);
    *reinterpret_cast<ushort4*>(fb + b * KP + p * 4) = o;
    if (p < 4)   // zero the K-pad 784..799
        *reinterpret_cast<ushort4*>(fb + b * KP + 784 + p * 4) = make_ushort4(0, 0, 0, 0);
}

// ---------------- Kernel 3: MFMA MLP ----------------
// Block = 256 threads = 4 waves, 16 samples x 128 units. Wave w owns cols
// [w*32, w*32+32) (2 fragments). K-loop = 5 chunks x 5 K-steps, register
// double-buffered (15 loads in flight while 10 MFMAs consume prev chunk).
// All buffer indices static (full unroll) so arrays stay in VGPRs.
__global__ __launch_bounds__(256) void mlp_mfma(
    const ushort* __restrict__ fb, const ushort* __restrict__ W1b,
    const float* __restrict__ b1, const ushort* __restrict__ W2b,
    const float* __restrict__ b2, float* __restrict__ out)
{
    __shared__ ushort Hs[16][136];

    const int t = threadIdx.x;
    const int l = t & 63;
    const int w = t >> 6;            // wave 0..3
    const int m0 = blockIdx.x * 16;
    const int row = l & 15;
    const int kg = l >> 4;

    f32x4 acc0 = {}, acc1 = {};
    const short8* ap  = reinterpret_cast<const short8*>(fb + (m0 + row) * KP + kg * 8);
    const short8* bp0 = reinterpret_cast<const short8*>(W1b + (w * 32 + row) * KP + kg * 8);
    const short8* bp1 = reinterpret_cast<const short8*>(W1b + (w * 32 + 16 + row) * KP + kg * 8);

    short8 A[2][5], B0[2][5], B1[2][5];
#pragma unroll
    for (int s = 0; s < 5; ++s) {
        A[0][s] = ap[s * 4]; B0[0][s] = bp0[s * 4]; B1[0][s] = bp1[s * 4];
    }
#pragma unroll
    for (int c = 0; c < 5; ++c) {
        const int cb = c & 1, nb = cb ^ 1;
        if (c < 4) {
#pragma unroll
            for (int s = 0; s < 5; ++s) {
                int ks = (c + 1) * 5 + s;
                A[nb][s]  = ap[ks * 4];
                B0[nb][s] = bp0[ks * 4];
                B1[nb][s] = bp1[ks * 4];
            }
        }
#pragma unroll
        for (int s = 0; s < 5; ++s) {
            acc0 = __builtin_amdgcn_mfma_f32_16x16x32_bf16(A[cb][s], B0[cb][s], acc0, 0, 0, 0);
            acc1 = __builtin_amdgcn_mfma_f32_16x16x32_bf16(A[cb][s], B1[cb][s], acc1, 0, 0, 0);
        }
    }

    // bias + relu -> Hs (bf16). C/D layout: col=l&15, row=(l>>4)*4+r.
    {
        int cc0 = w * 32 + row, cc1 = cc0 + 16;
        float bj0 = b1[cc0], bj1 = b1[cc1];
#pragma unroll
        for (int r = 0; r < 4; ++r) {
            int rr = kg * 4 + r;
            Hs[rr][cc0] = f2bf(fmaxf(acc0[r] + bj0, 0.0f));
            Hs[rr][cc1] = f2bf(fmaxf(acc1[r] + bj1, 0.0f));
        }
    }
    __syncthreads();

    // layer 2 (wave 0): D2[16 samples][16 j] = H(16x128) . W2b^T
    if (w == 0) {
        f32x4 acc2 = {};
#pragma unroll
        for (int ks = 0; ks < 4; ++ks) {
            short8 a = *reinterpret_cast<const short8*>(&Hs[row][ks * 32 + kg * 8]);
            short8 b = *reinterpret_cast<const short8*>(W2b + row * 128 + ks * 32 + kg * 8);
            acc2 = __builtin_amdgcn_mfma_f32_16x16x32_bf16(a, b, acc2, 0, 0, 0);
        }
        if (row < 10) {
            float bj = b2[row];
#pragma unroll
            for (int r = 0; r < 4; ++r)
                out[(m0 + kg * 4 + r) * 10 + row] = acc2[r] + bj;
        }
    }
}

extern "C" void kernel_launch(void* const* d_in, const int* in_sizes, int n_in,
                              void* d_out, int out_size, void* d_ws, size_t ws_size,
                              hipStream_t stream)
{
    const float* x  = (const float*)d_in[0];
    const float* qp = (const float*)d_in[1];
    const float* W1 = (const float*)d_in[2];
    const float* b1 = (const float*)d_in[3];
    const float* W2 = (const float*)d_in[4];
    const float* b2 = (const float*)d_in[5];
    float* out = (float*)d_out;

    ushort* fb  = (ushort*)d_ws;           // NB*KP bf16      = 6.55 MB
    ushort* W1b = fb + NB * KP;            // 128*KP bf16     = 0.20 MB
    ushort* W2b = W1b + 128 * KP;          // 16*128 bf16     = 4 KB
    float*  gtab = (float*)(W2b + 16 * 128);  // 7 floats

    conv_kernel<<<(128 * KP + 16 * 128 + 255) / 256, 256, 0, stream>>>(W1, W2, qp, W1b, W2b, gtab);
    quanv_kernel<<<(NB * NPATCH + 255) / 256, 256, 0, stream>>>(x, gtab, fb);
    mlp_mfma<<<NB / 16, 256, 0, stream>>>(fb, W1b, b1, W2b, b2, out);
}

// Round 13
// 78.518 us; speedup vs baseline: 1.6997x; 1.0209x over previous
//
#include <hip/hip_runtime.h>

#define NB 4096
#define NPATCH 196
#define KP 800            // K=784 zero-padded to 800 (25 x 32)
#define NCONV_BLK 408     // (128*KP + 16*128) / 256 = 104448/256

typedef __attribute__((ext_vector_type(8))) short short8;
typedef __attribute__((ext_vector_type(4))) float f32x4;

__device__ __forceinline__ ushort f2bf(float f) {
    unsigned b = __builtin_bit_cast(unsigned, f);
    b += 0x7FFFu + ((b >> 16) & 1u);   // RNE
    return (ushort)(b >> 16);
}

// ---------------- Kernel 1: fused prep (weight convert || quanvolution) ----
// Blocks [0,NCONV_BLK): W1 [128][784] -> W1b [128][KP] (zero-pad), W2 -> W2b.
// Blocks [NCONV_BLK, +3136): closed-form quanv, one thread per 2x2 patch.
//
// Circuit: RX0,RY1,RZ2 | CNOT01 | RX3 | CNOT23 | RY4(w0) | CNOT12.
// RX3 commutes w/ CNOT01; RY4 commutes w/ CNOT23. After RY4 only basis
// permutations remain -> phases never interfere: RZ2 drops out; q2,q3 enter
// via marginals only:
//   M = RY4 . CNOT01 . (u (x) v),  u = RX(t0)(c0,s0), v = RY(t1)(c1,s1)
//   Z0 = sum_b |M(0,b)|^2 - |M(1,b)|^2
//   Z1 = sum_a |M(a,0)|^2 - |M(a,1)|^2
//   Z2 = Z1 * cos(x2)
//   Z3 = cos(t3) * cos(x3) * cos(x2)
// Gate trig (5 uniform angles -> 7 values) recomputed per thread: ~28 cyc,
// removes the conv->quanv dependency so both halves run in one dispatch.
__global__ __launch_bounds__(256) void prep_kernel(
    const float* __restrict__ x, const float* __restrict__ qp,
    const float* __restrict__ W1, const float* __restrict__ W2,
    ushort* __restrict__ W1b, ushort* __restrict__ W2b,
    ushort* __restrict__ fb)
{
    if (blockIdx.x < NCONV_BLK) {
        int t = blockIdx.x * 256 + threadIdx.x;
        if (t < 128 * KP) {
            int r = t / KP, k = t - r * KP;
            W1b[t] = (k < 784) ? f2bf(W1[r * 784 + k]) : (ushort)0;
        } else {
            int u = t - 128 * KP;
            if (u < 16 * 128) W2b[u] = (u < 1280) ? f2bf(W2[u]) : (ushort)0;
        }
        return;
    }

    int t = (blockIdx.x - NCONV_BLK) * 256 + threadIdx.x;
    if (t >= NB * NPATCH) return;
    int b = t / NPATCH;
    int p = t - b * NPATCH;
    int pi = p / 14;
    int pj = p - pi * 14;

    const float* img = x + b * 784 + (2 * pi) * 28 + 2 * pj;
    float2 top = *reinterpret_cast<const float2*>(img);        // x0, x1
    float2 bot = *reinterpret_cast<const float2*>(img + 28);   // x2, x3

    float gs0 = __sinf(0.5f * qp[0]), gc0 = __cosf(0.5f * qp[0]);
    float gs1 = __sinf(0.5f * qp[1]), gc1 = __cosf(0.5f * qp[1]);
    float gs4 = __sinf(0.5f * qp[4]), gc4 = __cosf(0.5f * qp[4]);
    float ct3 = __cosf(qp[3]);

    float c0 = __cosf(0.5f * top.x), s0 = __sinf(0.5f * top.x);
    float c1 = __cosf(0.5f * top.y), s1 = __sinf(0.5f * top.y);
    float cz2 = __cosf(bot.x);
    float cz3 = __cosf(bot.y);

    // u = RX(t0) (c0,s0):  u0 = P - iQ,  u1 = m - i n
    float P = gc0 * c0, Q = gs0 * s0, m = gc0 * s0, n = gs0 * c0;
    // v = RY(t1) (c1,s1)  (real)
    float v0 = gc1 * c1 - gs1 * s1;
    float v1 = gs1 * c1 + gc1 * s1;

    // b=0 column: amp(0,0)=u0*v0, amp(1,0)=u1*v1 (CNOT01), then RY4 mix
    float a0 = gc4 * v0, b0 = gs4 * v1, g0 = gs4 * v0, d0 = gc4 * v1;
    float r, i2;
    r = a0 * P - b0 * m; i2 = a0 * Q - b0 * n; float P00 = r * r + i2 * i2;
    r = g0 * P + d0 * m; i2 = g0 * Q + d0 * n; float P10 = r * r + i2 * i2;
    // b=1 column: amp(0,1)=u0*v1, amp(1,1)=u1*v0
    float a1 = gc4 * v1, b1 = gs4 * v0, g1 = gs4 * v1, d1 = gc4 * v0;
    r = a1 * P - b1 * m; i2 = a1 * Q - b1 * n; float P01 = r * r + i2 * i2;
    r = g1 * P + d1 * m; i2 = g1 * Q + d1 * n; float P11 = r * r + i2 * i2;

    float z0 = (P00 + P01) - (P10 + P11);
    float z1 = (P00 + P10) - (P01 + P11);
    float z2 = z1 * cz2;
    float z3 = ct3 * cz3 * cz2;

    ushort4 o;
    o.x = f2bf(z0); o.y = f2bf(z1); o.z = f2bf(z2); o.w = f2bf(z3);
    *reinterpret_cast<ushort4*>(fb + b * KP + p * 4) = o;
    if (p < 4)   // zero the K-pad 784..799
        *reinterpret_cast<ushort4*>(fb + b * KP + 784 + p * 4) = make_ushort4(0, 0, 0, 0);
}

// ---------------- Kernel 2: MFMA MLP ----------------
// Block = 256 threads = 4 waves, 16 samples x 128 units. Wave w owns cols
// [w*32, w*32+32) (2 fragments). K-loop = 5 chunks x 5 K-steps, register
// double-buffered (15 loads in flight while 10 MFMAs consume prev chunk).
// All buffer indices static (full unroll) so arrays stay in VGPRs.
__global__ __launch_bounds__(256) void mlp_mfma(
    const ushort* __restrict__ fb, const ushort* __restrict__ W1b,
    const float* __restrict__ b1, const ushort* __restrict__ W2b,
    const float* __restrict__ b2, float* __restrict__ out)
{
    __shared__ ushort Hs[16][136];

    const int t = threadIdx.x;
    const int l = t & 63;
    const int w = t >> 6;            // wave 0..3
    const int m0 = blockIdx.x * 16;
    const int row = l & 15;
    const int kg = l >> 4;

    f32x4 acc0 = {}, acc1 = {};
    const short8* ap  = reinterpret_cast<const short8*>(fb + (m0 + row) * KP + kg * 8);
    const short8* bp0 = reinterpret_cast<const short8*>(W1b + (w * 32 + row) * KP + kg * 8);
    const short8* bp1 = reinterpret_cast<const short8*>(W1b + (w * 32 + 16 + row) * KP + kg * 8);

    short8 A[2][5], B0[2][5], B1[2][5];
#pragma unroll
    for (int s = 0; s < 5; ++s) {
        A[0][s] = ap[s * 4]; B0[0][s] = bp0[s * 4]; B1[0][s] = bp1[s * 4];
    }
#pragma unroll
    for (int c = 0; c < 5; ++c) {
        const int cb = c & 1, nb = cb ^ 1;
        if (c < 4) {
#pragma unroll
            for (int s = 0; s < 5; ++s) {
                int ks = (c + 1) * 5 + s;
                A[nb][s]  = ap[ks * 4];
                B0[nb][s] = bp0[ks * 4];
                B1[nb][s] = bp1[ks * 4];
            }
        }
#pragma unroll
        for (int s = 0; s < 5; ++s) {
            acc0 = __builtin_amdgcn_mfma_f32_16x16x32_bf16(A[cb][s], B0[cb][s], acc0, 0, 0, 0);
            acc1 = __builtin_amdgcn_mfma_f32_16x16x32_bf16(A[cb][s], B1[cb][s], acc1, 0, 0, 0);
        }
    }

    // bias + relu -> Hs (bf16). C/D layout: col=l&15, row=(l>>4)*4+r.
    {
        int cc0 = w * 32 + row, cc1 = cc0 + 16;
        float bj0 = b1[cc0], bj1 = b1[cc1];
#pragma unroll
        for (int r = 0; r < 4; ++r) {
            int rr = kg * 4 + r;
            Hs[rr][cc0] = f2bf(fmaxf(acc0[r] + bj0, 0.0f));
            Hs[rr][cc1] = f2bf(fmaxf(acc1[r] + bj1, 0.0f));
        }
    }
    __syncthreads();

    // layer 2 (wave 0): D2[16 samples][16 j] = H(16x128) . W2b^T
    if (w == 0) {
        f32x4 acc2 = {};
#pragma unroll
        for (int ks = 0; ks < 4; ++ks) {
            short8 a = *reinterpret_cast<const short8*>(&Hs[row][ks * 32 + kg * 8]);
            short8 b = *reinterpret_cast<const short8*>(W2b + row * 128 + ks * 32 + kg * 8);
            acc2 = __builtin_amdgcn_mfma_f32_16x16x32_bf16(a, b, acc2, 0, 0, 0);
        }
        if (row < 10) {
            float bj = b2[row];
#pragma unroll
            for (int r = 0; r < 4; ++r)
                out[(m0 + kg * 4 + r) * 10 + row] = acc2[r] + bj;
        }
    }
}

extern "C" void kernel_launch(void* const* d_in, const int* in_sizes, int n_in,
                              void* d_out, int out_size, void* d_ws, size_t ws_size,
                              hipStream_t stream)
{
    const float* x  = (const float*)d_in[0];
    const float* qp = (const float*)d_in[1];
    const float* W1 = (const float*)d_in[2];
    const float* b1 = (const float*)d_in[3];
    const float* W2 = (const float*)d_in[4];
    const float* b2 = (const float*)d_in[5];
    float* out = (float*)d_out;

    ushort* fb  = (ushort*)d_ws;           // NB*KP bf16      = 6.55 MB
    ushort* W1b = fb + NB * KP;            // 128*KP bf16     = 0.20 MB
    ushort* W2b = W1b + 128 * KP;          // 16*128 bf16     = 4 KB

    int quanv_blocks = (NB * NPATCH + 255) / 256;   // 3136
    prep_kernel<<<NCONV_BLK + quanv_blocks, 256, 0, stream>>>(x, qp, W1, W2, W1b, W2b, fb);
    mlp_mfma<<<NB / 16, 256, 0, stream>>>(fb, W1b, b1, W2b, b2, out);
}